// Round 3
// baseline (1991.858 us; speedup 1.0000x reference)
//
#include <hip/hip_runtime.h>

// Vector quantization: z [32768,256] f32, codebook [8192,256] f32
// outputs: z_q [32768,256] f32, indices [32768] (as float)
//
// Bitwise-replicates the float32 numpy reference:
//   d_k = fl32( fl32( Z_row - fl32(2*dot_k) ) + C_k ), argmin, first-index ties,
// with dot_k a sequential f32 FMA chain over d=0..255 (identical chain to the
// round-2 kernel that measured absmax 0).

#define NROWS 32768
#define DIM   256
#define KCB   8192
#define PITCH 132

// scratch inside z_q region of d_out (gather overwrites it last)
#define OFF_PM1 0         // [4][32768] per-split min
#define OFF_PI1 131072    // [4][32768] per-split idx (as float)
#define OFF_ZSQ 262144    // [32768] Z (np-pairwise f32)
#define OFF_CSQ 294912    // [8192]  C (np-pairwise f32)
#define OFF_IDX 8388608   // final indices (float), real output tail

// numpy pairwise sum of squares, n=256 contiguous, bitwise-faithful:
// 256 -> 128+128; each 128-block: 8 accumulators stride-8;
// combine ((r0+r1)+(r2+r3))+((r4+r5)+(r6+r7)); total = blk0+blk1.
__device__ float np_sumsq_256(const float* __restrict__ p) {
#pragma clang fp contract(off)
    float blk[2];
    #pragma unroll
    for (int b = 0; b < 2; ++b) {
        const float* q = p + b * 128;
        float r[8];
        #pragma unroll
        for (int j = 0; j < 8; ++j) r[j] = __fmul_rn(q[j], q[j]);
        for (int i = 8; i < 128; i += 8) {
            #pragma unroll
            for (int j = 0; j < 8; ++j)
                r[j] = __fadd_rn(r[j], __fmul_rn(q[i + j], q[i + j]));
        }
        blk[b] = __fadd_rn(
            __fadd_rn(__fadd_rn(r[0], r[1]), __fadd_rn(r[2], r[3])),
            __fadd_rn(__fadd_rn(r[4], r[5]), __fadd_rn(r[6], r[7])));
    }
    return __fadd_rn(blk[0], blk[1]);
}

__global__ void vq_sumsq_kernel(const float* __restrict__ a,
                                float* __restrict__ out, int nrows) {
    int r = blockIdx.x * blockDim.x + threadIdx.x;
    if (r < nrows) out[r] = np_sumsq_256(a + (size_t)r * DIM);
}

// Fused distance GEMM + per-row argmin.
// Grid (256 row-blocks, 4 k-splits), 256 threads = 8 row-thr(ty) x 32 code-thr(tx).
// Block tile: 128 rows x 2048 codes (16 strips of 128). Per thread: 16 rows x 4 codes.
#define FMAROW(zc, rr) \
    acc[rr][0] = fmaf(zc, e4.x, acc[rr][0]); \
    acc[rr][1] = fmaf(zc, e4.y, acc[rr][1]); \
    acc[rr][2] = fmaf(zc, e4.z, acc[rr][2]); \
    acc[rr][3] = fmaf(zc, e4.w, acc[rr][3]);

__global__ __launch_bounds__(256, 4) void vq_passA_kernel(
    const float* __restrict__ z, const float* __restrict__ cb,
    const float* __restrict__ csq32, const float* __restrict__ zsq32,
    float* __restrict__ pm1, float* __restrict__ pi1) {
    __shared__ float zT[32][PITCH];
    __shared__ float eT[32][PITCH];
    __shared__ float m1L[128];
    __shared__ int   i1L[128];
    const int tid = threadIdx.x;
    const int tx = tid & 31;     // code-thread
    const int ty = tid >> 5;     // row-thread, 0..7 (16 rows each)
    const int row0 = blockIdx.x * 128;
    const int cbase = blockIdx.y * 2048;

    if (tid < 128) { m1L[tid] = 3.4e38f; i1L[tid] = 0; }
    // ordering vs first epilogue is provided by the stage-loop barriers below

    for (int strip = 0; strip < 16; ++strip) {
        const int c0 = cbase + strip * 128;
        float acc[16][4];
        #pragma unroll
        for (int r = 0; r < 16; ++r)
            #pragma unroll
            for (int j = 0; j < 4; ++j) acc[r][j] = 0.0f;

        for (int dch = 0; dch < 8; ++dch) {
            const int d0 = dch * 32;
            __syncthreads();   // previous tile fully consumed
            #pragma unroll
            for (int p = 0; p < 4; ++p) {
                int f = tid + p * 256;          // 0..1023
                int rr = f >> 3, dg = f & 7;    // rr: row/code in tile, dg: d-group
                float4 v = *reinterpret_cast<const float4*>(
                    &z[(size_t)(row0 + rr) * DIM + d0 + dg * 4]);
                zT[dg * 4 + 0][rr] = v.x; zT[dg * 4 + 1][rr] = v.y;
                zT[dg * 4 + 2][rr] = v.z; zT[dg * 4 + 3][rr] = v.w;
                float4 e = *reinterpret_cast<const float4*>(
                    &cb[(size_t)(c0 + rr) * DIM + d0 + dg * 4]);
                eT[dg * 4 + 0][rr] = e.x; eT[dg * 4 + 1][rr] = e.y;
                eT[dg * 4 + 2][rr] = e.z; eT[dg * 4 + 3][rr] = e.w;
            }
            __syncthreads();
            #pragma unroll 8
            for (int d = 0; d < 32; ++d) {
                const float4 e4 = *reinterpret_cast<const float4*>(&eT[d][tx * 4]);
                const float4 z0 = *reinterpret_cast<const float4*>(&zT[d][ty * 16]);
                const float4 z1 = *reinterpret_cast<const float4*>(&zT[d][ty * 16 + 4]);
                const float4 z2 = *reinterpret_cast<const float4*>(&zT[d][ty * 16 + 8]);
                const float4 z3 = *reinterpret_cast<const float4*>(&zT[d][ty * 16 + 12]);
                FMAROW(z0.x, 0)  FMAROW(z0.y, 1)  FMAROW(z0.z, 2)  FMAROW(z0.w, 3)
                FMAROW(z1.x, 4)  FMAROW(z1.y, 5)  FMAROW(z1.z, 6)  FMAROW(z1.w, 7)
                FMAROW(z2.x, 8)  FMAROW(z2.y, 9)  FMAROW(z2.z, 10) FMAROW(z2.w, 11)
                FMAROW(z3.x, 12) FMAROW(z3.y, 13) FMAROW(z3.z, 14) FMAROW(z3.w, 15)
            }
        }
        // epilogue: d = fl(fl(Z - 2*dot) + C); per-thread c ascending (strict <
        // keeps lowest index on exact ties); then 32-lane argmin reduce.
        const int cthis = c0 + tx * 4;
        const float cs0 = csq32[cthis + 0];
        const float cs1 = csq32[cthis + 1];
        const float cs2 = csq32[cthis + 2];
        const float cs3 = csq32[cthis + 3];
        #pragma unroll
        for (int r = 0; r < 16; ++r) {
            const float Zr = zsq32[row0 + ty * 16 + r];
            float m = __fadd_rn(__fsub_rn(Zr, __fmul_rn(2.0f, acc[r][0])), cs0);
            int mi = cthis;
            float s;
            s = __fadd_rn(__fsub_rn(Zr, __fmul_rn(2.0f, acc[r][1])), cs1);
            if (s < m) { m = s; mi = cthis + 1; }
            s = __fadd_rn(__fsub_rn(Zr, __fmul_rn(2.0f, acc[r][2])), cs2);
            if (s < m) { m = s; mi = cthis + 2; }
            s = __fadd_rn(__fsub_rn(Zr, __fmul_rn(2.0f, acc[r][3])), cs3);
            if (s < m) { m = s; mi = cthis + 3; }
            #pragma unroll
            for (int st = 16; st >= 1; st >>= 1) {
                float o = __shfl_xor(m, st);
                int  oi = __shfl_xor(mi, st);
                if (o < m || (o == m && oi < mi)) { m = o; mi = oi; }
            }
            if (tx == 0) {
                int lr = ty * 16 + r;
                if (m < m1L[lr]) { m1L[lr] = m; i1L[lr] = mi; }  // tie -> earlier strip (lower c)
            }
        }
    }

    __syncthreads();
    if (tid < 128) {
        int o = blockIdx.y * NROWS + row0 + tid;
        pm1[o] = m1L[tid];
        pi1[o] = (float)i1L[tid];
    }
}

__global__ void vq_merge_kernel(const float* __restrict__ pm1,
                                const float* __restrict__ pi1,
                                float* __restrict__ outIdx) {
    int n = blockIdx.x * blockDim.x + threadIdx.x;
    float best = pm1[n]; int bi = (int)pi1[n];
    #pragma unroll
    for (int s2 = 1; s2 < 4; ++s2) {
        float v = pm1[s2 * NROWS + n];
        if (v < best) { best = v; bi = (int)pi1[s2 * NROWS + n]; }  // tie -> lower split
    }
    outIdx[n] = (float)bi;
}

__global__ void vq_gather_kernel(const float* __restrict__ cb,
                                 const float* __restrict__ idxF,
                                 float4* __restrict__ out4) {
    int g = blockIdx.x * blockDim.x + threadIdx.x;
    const float4* cb4 = reinterpret_cast<const float4*>(cb);
    for (int i = g; i < NROWS * 64; i += gridDim.x * blockDim.x) {
        int row = i >> 6, q = i & 63;
        int idx = (int)idxF[row];
        out4[i] = cb4[(size_t)idx * 64 + q];
    }
}

extern "C" void kernel_launch(void* const* d_in, const int* in_sizes, int n_in,
                              void* d_out, int out_size, void* d_ws, size_t ws_size,
                              hipStream_t stream) {
    const float* z  = (const float*)d_in[0];
    const float* cb = (const float*)d_in[1];
    float* out = (float*)d_out;

    float* pm1   = out + OFF_PM1;
    float* pi1   = out + OFF_PI1;
    float* zsq32 = out + OFF_ZSQ;
    float* csq32 = out + OFF_CSQ;
    float* idxF  = out + OFF_IDX;

    vq_sumsq_kernel<<<KCB / 256, 256, 0, stream>>>(cb, csq32, KCB);
    vq_sumsq_kernel<<<NROWS / 256, 256, 0, stream>>>(z, zsq32, NROWS);
    vq_passA_kernel<<<dim3(NROWS / 128, 4), 256, 0, stream>>>(z, cb, csq32, zsq32, pm1, pi1);
    vq_merge_kernel<<<NROWS / 256, 256, 0, stream>>>(pm1, pi1, idxF);
    vq_gather_kernel<<<2048, 256, 0, stream>>>(cb, idxF, (float4*)out);
}

// Round 4
// 923.940 us; speedup vs baseline: 2.1558x; 2.1558x over previous
//
#include <hip/hip_runtime.h>

// Vector quantization: z [32768,256] f32, codebook [8192,256] f32
// outputs: z_q [32768,256] f32, indices [32768] (as float)
//
// MFMA screening (3-pass bf16 split, guaranteed error bound) collects per-row
// candidates within MARGIN of the running min; an exact pass re-evaluates
// candidates with the bitwise round-2 f32 chain (sequential FMA d=0..255,
// d = fl(fl(Z - 2*dot) + C), first-index tie-break) which measured absmax 0.

#define NROWS 32768
#define DIM   256
#define KCB   8192

#define CANDCAP 64
#define MARGIN  2.5e-4f

// scratch inside z_q region of d_out (gather overwrites it last)
#define OFF_CAND 0          // u16 [32768][64] candidate code ids (4 MB)
#define OFF_CNT  1048576    // u32 [32768] per-row candidate count
#define OFF_ZSQ  1081344    // f32 [32768] Z (np-pairwise)
#define OFF_CSQ  1114112    // f32 [8192]  C (np-pairwise)
#define OFF_IDX  8388608    // final indices (float), real output tail

using bf16x8 = __attribute__((ext_vector_type(8))) short;
using f32x4  = __attribute__((ext_vector_type(4))) float;

__device__ __forceinline__ unsigned short bf16rne(float f) {
    unsigned u = __float_as_uint(f);
    unsigned r = u + 0x7FFFu + ((u >> 16) & 1u);
    return (unsigned short)(r >> 16);
}

// numpy pairwise sum of squares, n=256, bitwise-faithful (see round 2).
__device__ float np_sumsq_256(const float* __restrict__ p) {
#pragma clang fp contract(off)
    float blk[2];
    #pragma unroll
    for (int b = 0; b < 2; ++b) {
        const float* q = p + b * 128;
        float r[8];
        #pragma unroll
        for (int j = 0; j < 8; ++j) r[j] = __fmul_rn(q[j], q[j]);
        for (int i = 8; i < 128; i += 8) {
            #pragma unroll
            for (int j = 0; j < 8; ++j)
                r[j] = __fadd_rn(r[j], __fmul_rn(q[i + j], q[i + j]));
        }
        blk[b] = __fadd_rn(
            __fadd_rn(__fadd_rn(r[0], r[1]), __fadd_rn(r[2], r[3])),
            __fadd_rn(__fadd_rn(r[4], r[5]), __fadd_rn(r[6], r[7])));
    }
    return __fadd_rn(blk[0], blk[1]);
}

__global__ void vq_sumsq_kernel(const float* __restrict__ a,
                                float* __restrict__ out, int nrows) {
    int r = blockIdx.x * blockDim.x + threadIdx.x;
    if (r < nrows) out[r] = np_sumsq_256(a + (size_t)r * DIM);
}

__global__ void vq_init_kernel(unsigned* __restrict__ cnt) {
    int i = blockIdx.x * 256 + threadIdx.x;
    if (i < NROWS) cnt[i] = 0;
}

// ---------------- MFMA screening ----------------
// Block: 128 rows x all 8192 codes (32 tiles of 256). 512 thr = 8 waves (2x4).
// Wave sub-tile 64x64: acc[4][4] f32x4. BK=32, double-buffered LDS,
// reg-staged f32->bf16(h,l) conversion, XOR swizzle byte^=(row&7)<<4.
__global__ __launch_bounds__(512, 2) void vq_screen_kernel(
    const float* __restrict__ z, const float* __restrict__ cb,
    const float* __restrict__ zsq, const float* __restrict__ csq,
    unsigned* __restrict__ cnt, unsigned short* __restrict__ cand) {
    __shared__ __align__(16) unsigned short Ah[2][128 * 32];
    __shared__ __align__(16) unsigned short Al[2][128 * 32];
    __shared__ __align__(16) unsigned short Bh[2][256 * 32];
    __shared__ __align__(16) unsigned short Bl[2][256 * 32];
    __shared__ unsigned runminU[128];

    const int tid  = threadIdx.x;
    const int lane = tid & 63;
    const int wid  = tid >> 6;
    const int wr   = wid >> 2;   // 0..1 row-half
    const int wc   = wid & 3;    // 0..3 col-quarter
    const int row0 = blockIdx.x * 128;
    const int l15  = lane & 15;
    const int lhi  = lane >> 4;
    const int k0   = lhi * 8;

    if (tid < 128) runminU[tid] = 0x7F800000u;  // +inf

    float Zr[4][4];
    #pragma unroll
    for (int m = 0; m < 4; ++m)
        #pragma unroll
        for (int r = 0; r < 4; ++r)
            Zr[m][r] = zsq[row0 + wr * 64 + m * 16 + lhi * 4 + r];

    f32x4 acc[4][4];
    #pragma unroll
    for (int m = 0; m < 4; ++m)
        #pragma unroll
        for (int n = 0; n < 4; ++n) acc[m][n] = (f32x4){0.f, 0.f, 0.f, 0.f};

    float4 ra[2], rb[4];

    auto LOADS = [&](int s) {
        const int kk = s & 7, ct = s >> 3;
        #pragma unroll
        for (int p = 0; p < 2; ++p) {
            int g = tid + p * 512, rr = g >> 3, kq = g & 7;
            ra[p] = *reinterpret_cast<const float4*>(
                &z[(size_t)(row0 + rr) * DIM + kk * 32 + kq * 4]);
        }
        #pragma unroll
        for (int p = 0; p < 4; ++p) {
            int g = tid + p * 512, rr = g >> 3, kq = g & 7;
            rb[p] = *reinterpret_cast<const float4*>(
                &cb[(size_t)(ct * 256 + rr) * DIM + kk * 32 + kq * 4]);
        }
    };

    auto PUT = [&](unsigned short* dH, unsigned short* dL, int rr, int kq, float4 v) {
        unsigned short h0 = bf16rne(v.x), h1 = bf16rne(v.y);
        unsigned short h2 = bf16rne(v.z), h3 = bf16rne(v.w);
        float f0 = __uint_as_float(((unsigned)h0) << 16);
        float f1 = __uint_as_float(((unsigned)h1) << 16);
        float f2 = __uint_as_float(((unsigned)h2) << 16);
        float f3 = __uint_as_float(((unsigned)h3) << 16);
        unsigned short l0 = bf16rne(v.x - f0), l1 = bf16rne(v.y - f1);
        unsigned short l2 = bf16rne(v.z - f2), l3 = bf16rne(v.w - f3);
        int idx = (rr * 32 + kq * 4) ^ ((rr & 7) << 3);
        uint2 hw, lw;
        hw.x = (unsigned)h0 | ((unsigned)h1 << 16);
        hw.y = (unsigned)h2 | ((unsigned)h3 << 16);
        lw.x = (unsigned)l0 | ((unsigned)l1 << 16);
        lw.y = (unsigned)l2 | ((unsigned)l3 << 16);
        *reinterpret_cast<uint2*>(&dH[idx]) = hw;
        *reinterpret_cast<uint2*>(&dL[idx]) = lw;
    };

    auto WRITES = [&](int buf) {
        #pragma unroll
        for (int p = 0; p < 2; ++p) {
            int g = tid + p * 512;
            PUT(&Ah[buf][0], &Al[buf][0], g >> 3, g & 7, ra[p]);
        }
        #pragma unroll
        for (int p = 0; p < 4; ++p) {
            int g = tid + p * 512;
            PUT(&Bh[buf][0], &Bl[buf][0], g >> 3, g & 7, rb[p]);
        }
    };

    auto COMPUTE = [&](int buf) {
        bf16x8 ah[4], al[4], bh[4], bl[4];
        #pragma unroll
        for (int m = 0; m < 4; ++m) {
            int rr = wr * 64 + m * 16 + l15;
            int idx = (rr * 32 + k0) ^ ((rr & 7) << 3);
            ah[m] = *reinterpret_cast<const bf16x8*>(&Ah[buf][idx]);
            al[m] = *reinterpret_cast<const bf16x8*>(&Al[buf][idx]);
        }
        #pragma unroll
        for (int n = 0; n < 4; ++n) {
            int cc = wc * 64 + n * 16 + l15;
            int idx = (cc * 32 + k0) ^ ((cc & 7) << 3);
            bh[n] = *reinterpret_cast<const bf16x8*>(&Bh[buf][idx]);
            bl[n] = *reinterpret_cast<const bf16x8*>(&Bl[buf][idx]);
        }
        #pragma unroll
        for (int m = 0; m < 4; ++m)
            #pragma unroll
            for (int n = 0; n < 4; ++n) {
                acc[m][n] = __builtin_amdgcn_mfma_f32_16x16x32_bf16(ah[m], bh[n], acc[m][n], 0, 0, 0);
                acc[m][n] = __builtin_amdgcn_mfma_f32_16x16x32_bf16(ah[m], bl[n], acc[m][n], 0, 0, 0);
                acc[m][n] = __builtin_amdgcn_mfma_f32_16x16x32_bf16(al[m], bh[n], acc[m][n], 0, 0, 0);
            }
    };

    // s must use the SAME rounding ops as the exact chain epilogue.
    auto SVAL = [&](float a, float zr, float cs) {
        return __fadd_rn(__fsub_rn(zr, __fmul_rn(2.0f, a)), cs);
    };

    LOADS(0);
    __syncthreads();          // runminU init visible
    WRITES(0);
    __syncthreads();

    for (int s = 0; s < 256; ++s) {
        const int buf = s & 1, kk = s & 7, ct = s >> 3;
        if (s < 255) LOADS(s + 1);
        COMPUTE(buf);
        if (kk == 7) {
            // E1: fold this tile into per-row running min (incl. current tile)
            float cs[4];
            #pragma unroll
            for (int n = 0; n < 4; ++n) cs[n] = csq[ct * 256 + wc * 64 + n * 16 + l15];
            #pragma unroll
            for (int m = 0; m < 4; ++m)
                #pragma unroll
                for (int r = 0; r < 4; ++r) {
                    float v = SVAL(acc[m][0][r], Zr[m][r], cs[0]);
                    v = fminf(v, SVAL(acc[m][1][r], Zr[m][r], cs[1]));
                    v = fminf(v, SVAL(acc[m][2][r], Zr[m][r], cs[2]));
                    v = fminf(v, SVAL(acc[m][3][r], Zr[m][r], cs[3]));
                    #pragma unroll
                    for (int mk = 1; mk < 16; mk <<= 1) v = fminf(v, __shfl_xor(v, mk));
                    if (l15 == 0)
                        atomicMin(&runminU[wr * 64 + m * 16 + lhi * 4 + r], __float_as_uint(v));
                }
        }
        __syncthreads();
        if (s < 255) WRITES((s + 1) & 1);
        if (kk == 7) {
            // E2: collect candidates within MARGIN of running min
            float cs[4];
            #pragma unroll
            for (int n = 0; n < 4; ++n) cs[n] = csq[ct * 256 + wc * 64 + n * 16 + l15];
            #pragma unroll
            for (int m = 0; m < 4; ++m)
                #pragma unroll
                for (int r = 0; r < 4; ++r) {
                    int lrow = wr * 64 + m * 16 + lhi * 4 + r;
                    float rm = __uint_as_float(runminU[lrow]);
                    #pragma unroll
                    for (int n = 0; n < 4; ++n) {
                        float sv = SVAL(acc[m][n][r], Zr[m][r], cs[n]);
                        if (sv < rm + MARGIN) {
                            int grow = row0 + lrow;
                            unsigned slot = atomicAdd(&cnt[grow], 1u);
                            if (slot < CANDCAP)
                                cand[(size_t)grow * CANDCAP + slot] =
                                    (unsigned short)(ct * 256 + wc * 64 + n * 16 + l15);
                        }
                    }
                }
            #pragma unroll
            for (int m = 0; m < 4; ++m)
                #pragma unroll
                for (int n = 0; n < 4; ++n) acc[m][n] = (f32x4){0.f, 0.f, 0.f, 0.f};
        }
        __syncthreads();
    }
}

// ---------------- exact resolve ----------------
// One wave per row; lane j evaluates candidate j with the bitwise round-2
// chain. Overflow/empty -> full 8192-code scan. First-index tie-break.
__global__ __launch_bounds__(256) void vq_exact_kernel(
    const float* __restrict__ z, const float* __restrict__ cb,
    const float* __restrict__ zsq, const float* __restrict__ csq,
    const unsigned* __restrict__ cnt, const unsigned short* __restrict__ cand,
    float* __restrict__ idxF) {
    __shared__ float zrow[4][DIM];
    const int wid = threadIdx.x >> 6, lane = threadIdx.x & 63;
    const int row = blockIdx.x * 4 + wid;

    float4 zv4 = *reinterpret_cast<const float4*>(&z[(size_t)row * DIM + lane * 4]);
    *reinterpret_cast<float4*>(&zrow[wid][lane * 4]) = zv4;
    __syncthreads();

    const float Zr = zsq[row];
    const float4* cb4 = reinterpret_cast<const float4*>(cb);
    float best = 3.4e38f;
    int   bi   = 0x7FFFFFFF;
    const unsigned c = cnt[row];

    if (c > 0 && c <= CANDCAP) {
        if (lane < (int)c) {
            int k = cand[(size_t)row * CANDCAP + lane];
            float a = 0.0f;
            #pragma unroll 8
            for (int q = 0; q < 64; ++q) {
                float4 cv = cb4[(size_t)k * 64 + q];
                float4 zv = *reinterpret_cast<const float4*>(&zrow[wid][q * 4]);
                a = fmaf(zv.x, cv.x, a); a = fmaf(zv.y, cv.y, a);
                a = fmaf(zv.z, cv.z, a); a = fmaf(zv.w, cv.w, a);
            }
            best = __fadd_rn(__fsub_rn(Zr, __fmul_rn(2.0f, a)), csq[k]);
            bi = k;
        }
    } else {
        for (int k = lane; k < KCB; k += 64) {
            float a = 0.0f;
            #pragma unroll 8
            for (int q = 0; q < 64; ++q) {
                float4 cv = cb4[(size_t)k * 64 + q];
                float4 zv = *reinterpret_cast<const float4*>(&zrow[wid][q * 4]);
                a = fmaf(zv.x, cv.x, a); a = fmaf(zv.y, cv.y, a);
                a = fmaf(zv.z, cv.z, a); a = fmaf(zv.w, cv.w, a);
            }
            float sv = __fadd_rn(__fsub_rn(Zr, __fmul_rn(2.0f, a)), csq[k]);
            if (sv < best || (sv == best && k < bi)) { best = sv; bi = k; }
        }
    }
    #pragma unroll
    for (int mk = 32; mk >= 1; mk >>= 1) {
        float ov = __shfl_xor(best, mk);
        int   oi = __shfl_xor(bi, mk);
        if (ov < best || (ov == best && oi < bi)) { best = ov; bi = oi; }
    }
    if (lane == 0) idxF[row] = (float)bi;
}

__global__ void vq_gather_kernel(const float* __restrict__ cb,
                                 const float* __restrict__ idxF,
                                 float4* __restrict__ out4) {
    int g = blockIdx.x * blockDim.x + threadIdx.x;
    const float4* cb4 = reinterpret_cast<const float4*>(cb);
    for (int i = g; i < NROWS * 64; i += gridDim.x * blockDim.x) {
        int row = i >> 6, q = i & 63;
        int idx = (int)idxF[row];
        out4[i] = cb4[(size_t)idx * 64 + q];
    }
}

extern "C" void kernel_launch(void* const* d_in, const int* in_sizes, int n_in,
                              void* d_out, int out_size, void* d_ws, size_t ws_size,
                              hipStream_t stream) {
    const float* z  = (const float*)d_in[0];
    const float* cb = (const float*)d_in[1];
    float* out = (float*)d_out;

    unsigned short* candp = (unsigned short*)(out + OFF_CAND);
    unsigned*       cntp  = (unsigned*)(out + OFF_CNT);
    float*          zsq   = out + OFF_ZSQ;
    float*          csq   = out + OFF_CSQ;
    float*          idxF  = out + OFF_IDX;

    vq_sumsq_kernel<<<KCB / 256, 256, 0, stream>>>(cb, csq, KCB);
    vq_sumsq_kernel<<<NROWS / 256, 256, 0, stream>>>(z, zsq, NROWS);
    vq_init_kernel<<<NROWS / 256, 256, 0, stream>>>(cntp);
    vq_screen_kernel<<<NROWS / 128, 512, 0, stream>>>(z, cb, zsq, csq, cntp, candp);
    vq_exact_kernel<<<NROWS / 4, 256, 0, stream>>>(z, cb, zsq, csq, cntp, candp, idxF);
    vq_gather_kernel<<<2048, 256, 0, stream>>>(cb, idxF, (float4*)out);
}